// Round 3
// baseline (257.495 us; speedup 1.0000x reference)
//
#include <hip/hip_runtime.h>

#pragma clang fp contract(off)

#define HH 1024
#define WW 1024
#define HWSZ (HH * WW)
#define NB 16
#define CHUNKS 128                       // blocks per batch
#define THREADS 256
#define PIX_PER_BLOCK (HWSZ / CHUNKS)    // 8192
#define ITERS (PIX_PER_BLOCK / (THREADS * 4))  // 8
#define NBLK (CHUNKS * NB)               // 2048 stage-1 blocks
#define TPAD 8                           // zero-padding offset in tile
#define TDIM 32                          // tile dim (float2), 8 KiB LDS

// Faithful grid_sample corner path (zeros padding), reads global. Essentially
// never executed for this data (|coord| <= ~6), but guarantees correctness.
__device__ __attribute__((noinline)) float2 bilin_global(
    const float* __restrict__ p0, const float* __restrict__ p1,
    float x, float y) {
  float x0f = floorf(x), y0f = floorf(y);
  float wx = x - x0f, wy = y - y0f;
  float u0 = 1.f - wx, v0 = 1.f - wy;
  int ix = (int)x0f, iy = (int)y0f;
  float rx = 0.f, ry = 0.f;
  const int cxs[2] = {ix, ix + 1};
  const int cys[2] = {iy, iy + 1};
  const float wxs[2] = {u0, wx};
  const float wys[2] = {v0, wy};
#pragma unroll
  for (int jy = 0; jy < 2; jy++)
#pragma unroll
    for (int jx = 0; jx < 2; jx++) {
      int cx = cxs[jx], cy = cys[jy];
      bool inb = (cx >= 0) & (cx < WW) & (cy >= 0) & (cy < HH);
      int ccx = min(max(cx, 0), WW - 1);
      int ccy = min(max(cy, 0), HH - 1);
      float wm = (wxs[jx] * wys[jy]) * (inb ? 1.f : 0.f);
      rx += p0[ccy * WW + ccx] * wm;
      ry += p1[ccy * WW + ccx] * wm;
    }
  return make_float2(rx, ry);
}

// Fast path: zero-padded LDS tile covers image region [0,24)x[0,24) at
// tile[y+8][x+8]; rows/cols 0..7 are zeros so out-of-bounds (negative side)
// corners contribute 0 with no mask ops, matching zeros-padding semantics.
__device__ __forceinline__ float2 bilin(
    const float2 (*__restrict__ tile)[TDIM],
    const float* __restrict__ p0, const float* __restrict__ p1,
    float x, float y) {
  float x0f = floorf(x), y0f = floorf(y);
  float wx = x - x0f, wy = y - y0f;
  int px0 = (int)x0f + TPAD;
  int py0 = (int)y0f + TPAD;
  if (__builtin_expect(((unsigned)px0 > (unsigned)(TDIM - 2)) |
                       ((unsigned)py0 > (unsigned)(TDIM - 2)), 0))
    return bilin_global(p0, p1, x, y);
  float u0 = 1.f - wx;
  float v0 = 1.f - wy;
  float w00 = u0 * v0, w10 = wx * v0, w01 = u0 * wy, w11 = wx * wy;
  float2 s00 = tile[py0][px0];
  float2 s10 = tile[py0][px0 + 1];
  float2 s01 = tile[py0 + 1][px0];
  float2 s11 = tile[py0 + 1][px0 + 1];
  float2 r;
  // corner order + left-assoc sum matches reference exactly (contract off)
  r.x = s00.x * w00 + s10.x * w10 + s01.x * w01 + s11.x * w11;
  r.y = s00.y * w00 + s10.y * w10 + s01.y * w01 + s11.y * w11;
  return r;
}

__global__ __launch_bounds__(THREADS) void gs_diff_kernel(
    const float* __restrict__ in, double* __restrict__ partial) {
  const int b = blockIdx.y;
  const int chunk = blockIdx.x;
  const float* p0 = in + (size_t)b * (2 * HWSZ);
  const float* p1 = p0 + HWSZ;

  __shared__ float2 tile[TDIM][TDIM];
  const int t = threadIdx.x;
#pragma unroll
  for (int i = t; i < TDIM * TDIM; i += THREADS) {
    int py = i >> 5, px = i & 31;
    float a = 0.f, c = 0.f;
    if (py >= TPAD && px >= TPAD) {
      int yy = py - TPAD, xx = px - TPAD;
      a = p0[yy * WW + xx];
      c = p1[yy * WW + xx];
    }
    tile[py][px] = make_float2(a, c);
  }
  __syncthreads();

  float acc0 = 0.f, acc1 = 0.f, acc2 = 0.f, acc3 = 0.f;
  int base = chunk * PIX_PER_BLOCK + t * 4;

#define PIXEL(vx, vy)                                                        \
  {                                                                          \
    /* grid1 = ((v+0.5)/1024)*2 - 1 ; /1024 and *2 are pow2-exact, so       \
       (v+0.5)*(1/512) is bit-identical */                                   \
    float s1x = ((vx) + 0.5f) * (1.0f / 512.0f);                             \
    float t1x = (s1x - 1.0f) + 1.0f; /* (gx+1) with ref rounding */          \
    float s1y = ((vy) + 0.5f) * (1.0f / 512.0f);                             \
    float t1y = (s1y - 1.0f) + 1.0f;                                         \
    /* grid2 = v/1023*2 - 1 ; true IEEE division to match reference */       \
    float s2x = (vx) / 1023.0f;                                              \
    float t2x = ((s2x * 2.0f) - 1.0f) + 1.0f;                                \
    float s2y = (vy) / 1023.0f;                                              \
    float t2y = ((s2y * 2.0f) - 1.0f) + 1.0f;                                \
    /* aF: ((g+1)*1024 - 1)*0.5 ; aT: ((g+1)*0.5)*1023 == (g+1)*511.5       \
       (t*0.5 exact => single rounding either way) */                        \
    float x1 = (t1x * 1024.0f - 1.0f) * 0.5f;                                \
    float y1 = (t1y * 1024.0f - 1.0f) * 0.5f;                                \
    float x2 = t2x * 511.5f;                                                 \
    float y2 = t2y * 511.5f;                                                 \
    float x3 = t1x * 511.5f;                                                 \
    float y3 = t1y * 511.5f;                                                 \
    float x4 = (t2x * 1024.0f - 1.0f) * 0.5f;                                \
    float y4 = (t2y * 1024.0f - 1.0f) * 0.5f;                                \
    float2 r;                                                                \
    r = bilin(tile, p0, p1, x1, y1);                                         \
    acc0 += fabsf(r.x - (vx)) + fabsf(r.y - (vy));                           \
    r = bilin(tile, p0, p1, x2, y2);                                         \
    acc1 += fabsf(r.x - (vx)) + fabsf(r.y - (vy));                           \
    r = bilin(tile, p0, p1, x3, y3);                                         \
    acc2 += fabsf(r.x - (vx)) + fabsf(r.y - (vy));                           \
    r = bilin(tile, p0, p1, x4, y4);                                         \
    acc3 += fabsf(r.x - (vx)) + fabsf(r.y - (vy));                           \
  }

  for (int j = 0; j < ITERS; j++, base += THREADS * 4) {
    float4 X = *(const float4*)(p0 + base);
    float4 Y = *(const float4*)(p1 + base);
    PIXEL(X.x, Y.x);
    PIXEL(X.y, Y.y);
    PIXEL(X.z, Y.z);
    PIXEL(X.w, Y.w);
  }
#undef PIXEL

  // wave(64) butterfly reduce, then cross-wave via LDS
#pragma unroll
  for (int m = 1; m < 64; m <<= 1) {
    acc0 += __shfl_xor(acc0, m, 64);
    acc1 += __shfl_xor(acc1, m, 64);
    acc2 += __shfl_xor(acc2, m, 64);
    acc3 += __shfl_xor(acc3, m, 64);
  }
  __shared__ float wpart[4][4];  // [wave][variant]
  int lane = t & 63, wid = t >> 6;
  if (lane == 0) {
    wpart[wid][0] = acc0;
    wpart[wid][1] = acc1;
    wpart[wid][2] = acc2;
    wpart[wid][3] = acc3;
  }
  __syncthreads();
  if (t < 4) {
    double s = (double)wpart[0][t] + (double)wpart[1][t] +
               (double)wpart[2][t] + (double)wpart[3][t];
    partial[t * NBLK + blockIdx.y * CHUNKS + blockIdx.x] = s;
  }
}

__global__ __launch_bounds__(256) void gs_reduce_kernel(
    const double* __restrict__ partial, float* __restrict__ out) {
  const int v = blockIdx.x;  // variant 0..3
  const int t = threadIdx.x;
  double s = 0.0;
  for (int i = t; i < NBLK; i += 256) s += partial[v * NBLK + i];
#pragma unroll
  for (int m = 1; m < 64; m <<= 1) s += __shfl_xor(s, m, 64);
  __shared__ double ws[4];
  if ((t & 63) == 0) ws[t >> 6] = s;
  __syncthreads();
  if (t == 0) out[v] = (float)(ws[0] + ws[1] + ws[2] + ws[3]);
}

extern "C" void kernel_launch(void* const* d_in, const int* in_sizes, int n_in,
                              void* d_out, int out_size, void* d_ws,
                              size_t ws_size, hipStream_t stream) {
  const float* in = (const float*)d_in[0];
  float* out = (float*)d_out;
  double* partial = (double*)d_ws;  // 4 * 2048 doubles = 64 KiB

  dim3 g1(CHUNKS, NB);
  gs_diff_kernel<<<g1, THREADS, 0, stream>>>(in, partial);
  gs_reduce_kernel<<<4, 256, 0, stream>>>(partial, out);
}

// Round 4
// 227.314 us; speedup vs baseline: 1.1328x; 1.1328x over previous
//
#include <hip/hip_runtime.h>

#pragma clang fp contract(off)

#define HH 1024
#define WW 1024
#define HWSZ (HH * WW)
#define NB 16
#define CHUNKS 128                       // blocks per batch
#define THREADS 256
#define PIX_PER_BLOCK (HWSZ / CHUNKS)    // 8192
#define ITERS (PIX_PER_BLOCK / (THREADS * 4))  // 8
#define NBLK (CHUNKS * NB)               // 2048 stage-1 blocks
#define TPAD 8                           // zero-padding offset in tile
#define TDIM 32                          // tile dim, window covers [-8,24)
#define TSTRIDE 37                       // row stride in floats; 37%32=5 spreads banks
#define PLANE (TDIM * TSTRIDE)           // 1184 floats per channel plane

// Correctly-rounded x/1023 via 2-step fma refinement (Markstein).
// r = RN(1/1023); two Newton/fma steps give the RN quotient (5 ops vs ~15
// for the compiler's div_scale/div_fmas/div_fixup expansion).
__device__ __forceinline__ float div1023(float x) {
  const float r = (float)(1.0 / 1023.0);
  float q = x * r;
  float e = fmaf(-1023.0f, q, x);
  q = fmaf(e, r, q);
  e = fmaf(-1023.0f, q, x);
  q = fmaf(e, r, q);
  return q;
}

// Faithful grid_sample corner path (zeros padding), reads global. Essentially
// never executed for this data (|coord| <= ~7), but guarantees correctness.
__device__ __attribute__((noinline)) float2 bilin_global(
    const float* __restrict__ p0, const float* __restrict__ p1,
    float x, float y) {
  float x0f = floorf(x), y0f = floorf(y);
  float wx = x - x0f, wy = y - y0f;
  float u0 = 1.f - wx, v0 = 1.f - wy;
  int ix = (int)x0f, iy = (int)y0f;
  float rx = 0.f, ry = 0.f;
  const int cxs[2] = {ix, ix + 1};
  const int cys[2] = {iy, iy + 1};
  const float wxs[2] = {u0, wx};
  const float wys[2] = {v0, wy};
#pragma unroll
  for (int jy = 0; jy < 2; jy++)
#pragma unroll
    for (int jx = 0; jx < 2; jx++) {
      int cx = cxs[jx], cy = cys[jy];
      bool inb = (cx >= 0) & (cx < WW) & (cy >= 0) & (cy < HH);
      int ccx = min(max(cx, 0), WW - 1);
      int ccy = min(max(cy, 0), HH - 1);
      float wm = (wxs[jx] * wys[jy]) * (inb ? 1.f : 0.f);
      rx += p0[ccy * WW + ccx] * wm;
      ry += p1[ccy * WW + ccx] * wm;
    }
  return make_float2(rx, ry);
}

// Fast path: zero-padded planes cover image region [0,24)x[0,24) at
// plane[(y+8)*37 + (x+8)]; border rows/cols are zeros so negative-side
// out-of-bounds corners contribute 0 with no masking, matching zeros padding.
// Corner order + left-assoc sums match the reference exactly (contract off).
__device__ __forceinline__ void sample_fast(
    const float* __restrict__ t0, const float* __restrict__ t1,
    float x, float y, float vx, float vy, float& accx, float& accy) {
  float x0f = floorf(x), y0f = floorf(y);
  float wx = x - x0f, wy = y - y0f;
  int idx = (int)y0f * TSTRIDE + (int)x0f + (TPAD * TSTRIDE + TPAD);
  float u0 = 1.f - wx, v0 = 1.f - wy;
  float w00 = u0 * v0, w10 = wx * v0, w01 = u0 * wy, w11 = wx * wy;
  float a00 = t0[idx], a10 = t0[idx + 1];
  float a01 = t0[idx + TSTRIDE], a11 = t0[idx + TSTRIDE + 1];
  float b00 = t1[idx], b10 = t1[idx + 1];
  float b01 = t1[idx + TSTRIDE], b11 = t1[idx + TSTRIDE + 1];
  float rx = ((a00 * w00 + a10 * w10) + a01 * w01) + a11 * w11;
  float ry = ((b00 * w00 + b10 * w10) + b01 * w01) + b11 * w11;
  accx += fabsf(rx - vx);  // fabs folds into operand modifier
  accy += fabsf(ry - vy);
}

__global__ __launch_bounds__(THREADS) void gs_diff_kernel(
    const float* __restrict__ in, double* __restrict__ partial) {
  const int b = blockIdx.y;
  const int chunk = blockIdx.x;
  const float* p0 = in + (size_t)b * (2 * HWSZ);
  const float* p1 = p0 + HWSZ;

  __shared__ float tile0[PLANE];
  __shared__ float tile1[PLANE];
  const int t = threadIdx.x;
#pragma unroll
  for (int i = t; i < TDIM * TDIM; i += THREADS) {
    int py = i >> 5, px = i & 31;
    float a = 0.f, c = 0.f;
    if (py >= TPAD && px >= TPAD) {
      int yy = py - TPAD, xx = px - TPAD;
      a = p0[yy * WW + xx];
      c = p1[yy * WW + xx];
    }
    tile0[py * TSTRIDE + px] = a;
    tile1[py * TSTRIDE + px] = c;
  }
  __syncthreads();

  float acc0x = 0.f, acc0y = 0.f, acc1x = 0.f, acc1y = 0.f;
  float acc2x = 0.f, acc2y = 0.f, acc3x = 0.f, acc3y = 0.f;
  int base = chunk * PIX_PER_BLOCK + t * 4;

#define PIXEL(vx, vy)                                                        \
  {                                                                          \
    /* grid1 = ((v+0.5)/1024)*2 - 1 ; /1024,*2 pow2-exact => *(1/512) */     \
    float s1x = ((vx) + 0.5f) * (1.0f / 512.0f);                             \
    float t1x = (s1x - 1.0f) + 1.0f; /* (gx+1) with ref rounding */          \
    float s1y = ((vy) + 0.5f) * (1.0f / 512.0f);                             \
    float t1y = (s1y - 1.0f) + 1.0f;                                         \
    /* grid2 = v/1023*2 - 1 ; correctly-rounded division */                  \
    float s2x = div1023(vx);                                                 \
    float t2x = ((s2x * 2.0f) - 1.0f) + 1.0f;                                \
    float s2y = div1023(vy);                                                 \
    float t2y = ((s2y * 2.0f) - 1.0f) + 1.0f;                                \
    /* aF: ((g+1)*1024 - 1)*0.5 ; aT: ((g+1)*0.5)*1023 == (g+1)*511.5 */     \
    float x1 = (t1x * 1024.0f - 1.0f) * 0.5f;                                \
    float y1 = (t1y * 1024.0f - 1.0f) * 0.5f;                                \
    float x2 = t2x * 511.5f;                                                 \
    float y2 = t2y * 511.5f;                                                 \
    float x3 = t1x * 511.5f;                                                 \
    float y3 = t1y * 511.5f;                                                 \
    float x4 = (t2x * 1024.0f - 1.0f) * 0.5f;                                \
    float y4 = (t2y * 1024.0f - 1.0f) * 0.5f;                                \
    /* one range check for all 8 coords (fmax/fmin fuse to v_max3) */        \
    float mx = fmaxf(fmaxf(fmaxf(x1, y1), fmaxf(x2, y2)),                    \
                     fmaxf(fmaxf(x3, y3), fmaxf(x4, y4)));                   \
    float mn = fminf(fminf(fminf(x1, y1), fminf(x2, y2)),                    \
                     fminf(fminf(x3, y3), fminf(x4, y4)));                   \
    if (__builtin_expect((mn < (float)(-TPAD)) |                             \
                         (mx >= (float)(TDIM - TPAD - 1)), 0)) {             \
      float2 r;                                                              \
      r = bilin_global(p0, p1, x1, y1);                                      \
      acc0x += fabsf(r.x - (vx)); acc0y += fabsf(r.y - (vy));                \
      r = bilin_global(p0, p1, x2, y2);                                      \
      acc1x += fabsf(r.x - (vx)); acc1y += fabsf(r.y - (vy));                \
      r = bilin_global(p0, p1, x3, y3);                                      \
      acc2x += fabsf(r.x - (vx)); acc2y += fabsf(r.y - (vy));                \
      r = bilin_global(p0, p1, x4, y4);                                      \
      acc3x += fabsf(r.x - (vx)); acc3y += fabsf(r.y - (vy));                \
    } else {                                                                 \
      sample_fast(tile0, tile1, x1, y1, (vx), (vy), acc0x, acc0y);           \
      sample_fast(tile0, tile1, x2, y2, (vx), (vy), acc1x, acc1y);           \
      sample_fast(tile0, tile1, x3, y3, (vx), (vy), acc2x, acc2y);           \
      sample_fast(tile0, tile1, x4, y4, (vx), (vy), acc3x, acc3y);           \
    }                                                                        \
  }

  for (int j = 0; j < ITERS; j++, base += THREADS * 4) {
    float4 X = *(const float4*)(p0 + base);
    float4 Y = *(const float4*)(p1 + base);
    PIXEL(X.x, Y.x);
    PIXEL(X.y, Y.y);
    PIXEL(X.z, Y.z);
    PIXEL(X.w, Y.w);
  }
#undef PIXEL

  float acc0 = acc0x + acc0y, acc1 = acc1x + acc1y;
  float acc2 = acc2x + acc2y, acc3 = acc3x + acc3y;

  // wave(64) butterfly reduce, then cross-wave via LDS
#pragma unroll
  for (int m = 1; m < 64; m <<= 1) {
    acc0 += __shfl_xor(acc0, m, 64);
    acc1 += __shfl_xor(acc1, m, 64);
    acc2 += __shfl_xor(acc2, m, 64);
    acc3 += __shfl_xor(acc3, m, 64);
  }
  __shared__ float wpart[4][4];  // [wave][variant]
  int lane = t & 63, wid = t >> 6;
  if (lane == 0) {
    wpart[wid][0] = acc0;
    wpart[wid][1] = acc1;
    wpart[wid][2] = acc2;
    wpart[wid][3] = acc3;
  }
  __syncthreads();
  if (t < 4) {
    double s = (double)wpart[0][t] + (double)wpart[1][t] +
               (double)wpart[2][t] + (double)wpart[3][t];
    partial[t * NBLK + blockIdx.y * CHUNKS + blockIdx.x] = s;
  }
}

__global__ __launch_bounds__(256) void gs_reduce_kernel(
    const double* __restrict__ partial, float* __restrict__ out) {
  const int v = blockIdx.x;  // variant 0..3
  const int t = threadIdx.x;
  double s = 0.0;
  for (int i = t; i < NBLK; i += 256) s += partial[v * NBLK + i];
#pragma unroll
  for (int m = 1; m < 64; m <<= 1) s += __shfl_xor(s, m, 64);
  __shared__ double ws[4];
  if ((t & 63) == 0) ws[t >> 6] = s;
  __syncthreads();
  if (t == 0) out[v] = (float)(ws[0] + ws[1] + ws[2] + ws[3]);
}

extern "C" void kernel_launch(void* const* d_in, const int* in_sizes, int n_in,
                              void* d_out, int out_size, void* d_ws,
                              size_t ws_size, hipStream_t stream) {
  const float* in = (const float*)d_in[0];
  float* out = (float*)d_out;
  double* partial = (double*)d_ws;  // 4 * 2048 doubles = 64 KiB

  dim3 g1(CHUNKS, NB);
  gs_diff_kernel<<<g1, THREADS, 0, stream>>>(in, partial);
  gs_reduce_kernel<<<4, 256, 0, stream>>>(partial, out);
}

// Round 5
// 216.585 us; speedup vs baseline: 1.1889x; 1.0495x over previous
//
#include <hip/hip_runtime.h>

#pragma clang fp contract(off)

#define HH 1024
#define WW 1024
#define HWSZ (HH * WW)
#define NB 16
#define CHUNKS 128                       // blocks per batch
#define THREADS 256
#define PIX_PER_BLOCK (HWSZ / CHUNKS)    // 8192
#define ITERS (PIX_PER_BLOCK / (THREADS * 4))  // 8
#define NBLK (CHUNKS * NB)               // 2048 stage-1 blocks
#define TPAD 8                           // zero-padding offset in tile
#define TDIM 32                          // tile dim, window covers [-8,24)
#define TSTRIDE 37                       // row stride in floats; 37%32=5 spreads banks
#define PLANE (TDIM * TSTRIDE)           // 1184 floats per channel plane

// Correctly-rounded x/1023 via 2-step fma refinement (Markstein), 5 ops.
__device__ __forceinline__ float div1023(float x) {
  const float r = (float)(1.0 / 1023.0);
  float q = x * r;
  float e = fmaf(-1023.0f, q, x);
  q = fmaf(e, r, q);
  e = fmaf(-1023.0f, q, x);
  q = fmaf(e, r, q);
  return q;
}

// Faithful grid_sample corner path (zeros padding), reads global. Essentially
// never executed for this data (|v| <= ~7 => in-window), but guarantees
// correctness for arbitrary coords.
__device__ __attribute__((noinline)) float2 bilin_global(
    const float* __restrict__ p0, const float* __restrict__ p1,
    float x, float y) {
  float x0f = floorf(x), y0f = floorf(y);
  float wx = x - x0f, wy = y - y0f;
  float u0 = 1.f - wx, v0 = 1.f - wy;
  int ix = (int)x0f, iy = (int)y0f;
  float rx = 0.f, ry = 0.f;
  const int cxs[2] = {ix, ix + 1};
  const int cys[2] = {iy, iy + 1};
  const float wxs[2] = {u0, wx};
  const float wys[2] = {v0, wy};
#pragma unroll
  for (int jy = 0; jy < 2; jy++)
#pragma unroll
    for (int jx = 0; jx < 2; jx++) {
      int cx = cxs[jx], cy = cys[jy];
      bool inb = (cx >= 0) & (cx < WW) & (cy >= 0) & (cy < HH);
      int ccx = min(max(cx, 0), WW - 1);
      int ccy = min(max(cy, 0), HH - 1);
      float wm = (wxs[jx] * wys[jy]) * (inb ? 1.f : 0.f);
      rx += p0[ccy * WW + ccx] * wm;
      ry += p1[ccy * WW + ccx] * wm;
    }
  return make_float2(rx, ry);
}

// Fast path: zero-padded planes cover image region [0,24)x[0,24) at
// plane[(y+8)*37 + (x+8)]; border rows/cols are zeros so negative-side
// out-of-bounds corners contribute 0 with no masking (zeros padding).
// Address via float fma (avoids v_mul_lo_u32); +1/+37/+38 are ds_read2
// immediate offsets. Interpolation uses fma chains (<=1ulp vs reference;
// coordinates feeding floor/weights remain bit-exact).
__device__ __forceinline__ void sample_fast(
    const float* __restrict__ t0, const float* __restrict__ t1,
    float x, float y, float vx, float vy, float& accx, float& accy) {
  float x0f = floorf(x), y0f = floorf(y);
  float wx = x - x0f, wy = y - y0f;
  int idx = (int)fmaf(y0f, (float)TSTRIDE, x0f) + (TPAD * TSTRIDE + TPAD);
  float u0 = 1.f - wx, v0 = 1.f - wy;
  float w00 = u0 * v0, w10 = wx * v0, w01 = u0 * wy, w11 = wx * wy;
  float a00 = t0[idx], a10 = t0[idx + 1];
  float a01 = t0[idx + TSTRIDE], a11 = t0[idx + TSTRIDE + 1];
  float b00 = t1[idx], b10 = t1[idx + 1];
  float b01 = t1[idx + TSTRIDE], b11 = t1[idx + TSTRIDE + 1];
  float rx = fmaf(a11, w11, fmaf(a01, w01, fmaf(a10, w10, a00 * w00)));
  float ry = fmaf(b11, w11, fmaf(b01, w01, fmaf(b10, w10, b00 * w00)));
  accx += fabsf(rx - vx);  // fabs folds into operand modifier
  accy += fabsf(ry - vy);
}

__global__ __launch_bounds__(THREADS) void gs_diff_kernel(
    const float* __restrict__ in, double* __restrict__ partial) {
  const int b = blockIdx.y;
  const int chunk = blockIdx.x;
  const float* p0 = in + (size_t)b * (2 * HWSZ);
  const float* p1 = p0 + HWSZ;

  __shared__ float tile0[PLANE];
  __shared__ float tile1[PLANE];
  const int t = threadIdx.x;
#pragma unroll
  for (int i = t; i < TDIM * TDIM; i += THREADS) {
    int py = i >> 5, px = i & 31;
    float a = 0.f, c = 0.f;
    if (py >= TPAD && px >= TPAD) {
      int yy = py - TPAD, xx = px - TPAD;
      a = p0[yy * WW + xx];
      c = p1[yy * WW + xx];
    }
    tile0[py * TSTRIDE + px] = a;
    tile1[py * TSTRIDE + px] = c;
  }
  __syncthreads();

  float acc0x = 0.f, acc0y = 0.f, acc1x = 0.f, acc1y = 0.f;
  float acc2x = 0.f, acc2y = 0.f, acc3x = 0.f, acc3y = 0.f;
  int base = chunk * PIX_PER_BLOCK + t * 4;

  // Coordinate math, bit-exact vs reference:
  //   s1 = (v+0.5)/512 == fmaf(v, 1/512, 1/1024)   (/512 exact bijection)
  //   t1 = (s1-1)+1                                 (ref rounding kept)
  //   aF: ((g+1)*1024-1)*0.5 == fmaf(t1, 512, -0.5) (pow2 scale commutes w/ RN)
  //   aT: ((g+1)*0.5)*1023 == (g+1)*511.5           (t*0.5 exact)
  //   s2 = v/1023 correctly rounded (div1023); t2 = fmaf(s2,2,-1)+1
  //      (s2*2 exact => fma == mul-then-sub of ref)
#define PIXEL(vx, vy)                                                        \
  {                                                                          \
    float s1x = fmaf((vx), (1.0f / 512.0f), (1.0f / 1024.0f));               \
    float t1x = (s1x - 1.0f) + 1.0f;                                         \
    float s1y = fmaf((vy), (1.0f / 512.0f), (1.0f / 1024.0f));               \
    float t1y = (s1y - 1.0f) + 1.0f;                                         \
    float s2x = div1023(vx);                                                 \
    float t2x = fmaf(s2x, 2.0f, -1.0f) + 1.0f;                               \
    float s2y = div1023(vy);                                                 \
    float t2y = fmaf(s2y, 2.0f, -1.0f) + 1.0f;                               \
    float x1 = fmaf(t1x, 512.0f, -0.5f);                                     \
    float y1 = fmaf(t1y, 512.0f, -0.5f);                                     \
    float x2 = t2x * 511.5f;                                                 \
    float y2 = t2y * 511.5f;                                                 \
    float x3 = t1x * 511.5f;                                                 \
    float y3 = t1y * 511.5f;                                                 \
    float x4 = fmaf(t2x, 512.0f, -0.5f);                                     \
    float y4 = fmaf(t2y, 512.0f, -0.5f);                                     \
    /* |v|<=7 => every coord in [-7.6,21.6] subset of window [-8,23) */      \
    float av = fmaxf(fabsf((vx)), fabsf((vy)));                              \
    if (__builtin_expect(av > 7.0f, 0)) {                                    \
      float2 r;                                                              \
      r = bilin_global(p0, p1, x1, y1);                                      \
      acc0x += fabsf(r.x - (vx)); acc0y += fabsf(r.y - (vy));                \
      r = bilin_global(p0, p1, x2, y2);                                      \
      acc1x += fabsf(r.x - (vx)); acc1y += fabsf(r.y - (vy));                \
      r = bilin_global(p0, p1, x3, y3);                                      \
      acc2x += fabsf(r.x - (vx)); acc2y += fabsf(r.y - (vy));                \
      r = bilin_global(p0, p1, x4, y4);                                      \
      acc3x += fabsf(r.x - (vx)); acc3y += fabsf(r.y - (vy));                \
    } else {                                                                 \
      sample_fast(tile0, tile1, x1, y1, (vx), (vy), acc0x, acc0y);           \
      sample_fast(tile0, tile1, x2, y2, (vx), (vy), acc1x, acc1y);           \
      sample_fast(tile0, tile1, x3, y3, (vx), (vy), acc2x, acc2y);           \
      sample_fast(tile0, tile1, x4, y4, (vx), (vy), acc3x, acc3y);           \
    }                                                                        \
  }

  for (int j = 0; j < ITERS; j++, base += THREADS * 4) {
    float4 X = *(const float4*)(p0 + base);
    float4 Y = *(const float4*)(p1 + base);
    PIXEL(X.x, Y.x);
    PIXEL(X.y, Y.y);
    PIXEL(X.z, Y.z);
    PIXEL(X.w, Y.w);
  }
#undef PIXEL

  float acc0 = acc0x + acc0y, acc1 = acc1x + acc1y;
  float acc2 = acc2x + acc2y, acc3 = acc3x + acc3y;

  // wave(64) butterfly reduce, then cross-wave via LDS
#pragma unroll
  for (int m = 1; m < 64; m <<= 1) {
    acc0 += __shfl_xor(acc0, m, 64);
    acc1 += __shfl_xor(acc1, m, 64);
    acc2 += __shfl_xor(acc2, m, 64);
    acc3 += __shfl_xor(acc3, m, 64);
  }
  __shared__ float wpart[4][4];  // [wave][variant]
  int lane = t & 63, wid = t >> 6;
  if (lane == 0) {
    wpart[wid][0] = acc0;
    wpart[wid][1] = acc1;
    wpart[wid][2] = acc2;
    wpart[wid][3] = acc3;
  }
  __syncthreads();
  if (t < 4) {
    double s = (double)wpart[0][t] + (double)wpart[1][t] +
               (double)wpart[2][t] + (double)wpart[3][t];
    partial[t * NBLK + blockIdx.y * CHUNKS + blockIdx.x] = s;
  }
}

__global__ __launch_bounds__(256) void gs_reduce_kernel(
    const double* __restrict__ partial, float* __restrict__ out) {
  const int v = blockIdx.x;  // variant 0..3
  const int t = threadIdx.x;
  double s = 0.0;
  for (int i = t; i < NBLK; i += 256) s += partial[v * NBLK + i];
#pragma unroll
  for (int m = 1; m < 64; m <<= 1) s += __shfl_xor(s, m, 64);
  __shared__ double ws[4];
  if ((t & 63) == 0) ws[t >> 6] = s;
  __syncthreads();
  if (t == 0) out[v] = (float)(ws[0] + ws[1] + ws[2] + ws[3]);
}

extern "C" void kernel_launch(void* const* d_in, const int* in_sizes, int n_in,
                              void* d_out, int out_size, void* d_ws,
                              size_t ws_size, hipStream_t stream) {
  const float* in = (const float*)d_in[0];
  float* out = (float*)d_out;
  double* partial = (double*)d_ws;  // 4 * 2048 doubles = 64 KiB

  dim3 g1(CHUNKS, NB);
  gs_diff_kernel<<<g1, THREADS, 0, stream>>>(in, partial);
  gs_reduce_kernel<<<4, 256, 0, stream>>>(partial, out);
}